// Round 3
// baseline (282.770 us; speedup 1.0000x reference)
//
#include <hip/hip_runtime.h>

#define NA 1024
#define NBATCH 4
#define NPAIR 523776           // NA*(NA-1)/2
#define PAIR_BLOCKS 1023       // each does 4 tiles of 128 pairs (exact cover)
#define GRID_X 1025            // + 2 atom blocks (each 4 tiles of 128 atoms)

// ws layout (byte offsets)
#define WS_MEAN 0              // 8 floats (per-batch mean x,y)
#define WS_W0P  64             // 2048 halves: pair W0eff frags
#define WS_W0A  4160           // 2048 halves: atom W0eff frags
#define WS_W1P  8256           // 4096 halves: pair W1 frags
#define WS_W1A  16448          // 4096 halves: atom W1 frags

typedef _Float16 half8 __attribute__((ext_vector_type(8)));
typedef float float4v __attribute__((ext_vector_type(4)));

__device__ __forceinline__ float silu_f(float x) {
    return x * __builtin_amdgcn_rcpf(1.0f + __expf(-x));
}

__device__ __forceinline__ uint32_t pkf16(float a, float b) {
    union { _Float16 h[2]; uint32_t u; } x;
    x.h[0] = (_Float16)a; x.h[1] = (_Float16)b;   // RTNE
    return x.u;
}

// XOR-swizzled LDS offset (in halves): row stride 64, 16B chunk swizzle.
// Keeps every b128 access (A write/read, H read) at the 8-clk bank floor.
__device__ __forceinline__ int lds_off(int row, int chunk) {
    return (row << 6) + ((chunk ^ (row & 7)) << 3);
}

// ---------------------------------------------------------------------------
// prep: blocks 0..3 -> per-batch mean + out[b] init; block 4 -> weight packing.
// W0eff rows (K=14 live, padded to 32): 0..4 = raw feature rows, 5 = 0,
// 6..9 = one-hot(i) rows (embed@W0 folded), 10..13 = one-hot(j) rows (pair
// only). Frag order: [(nt*64+lane)*8+j] = W[(lane>>4)*8+j][nt*16+(lane&15)]
// ---------------------------------------------------------------------------
__global__ void prep_kernel(const float* __restrict__ positions,
                            const float* __restrict__ embed,
                            const float* __restrict__ aW0,
                            const float* __restrict__ aW1,
                            const float* __restrict__ ab2,
                            const float* __restrict__ pW0,
                            const float* __restrict__ pW1,
                            const float* __restrict__ pb2,
                            char* __restrict__ ws,
                            float* __restrict__ out) {
    const int tid = threadIdx.x;
    if (blockIdx.x < 4) {
        const int b = blockIdx.x;
        const float2* pos = (const float2*)positions + b * NA;
        float sx = 0.f, sy = 0.f;
        for (int t = tid; t < NA; t += 256) {
            float2 p = pos[t];
            sx += p.x; sy += p.y;
        }
#pragma unroll
        for (int off = 32; off > 0; off >>= 1) {
            sx += __shfl_down(sx, off);
            sy += __shfl_down(sy, off);
        }
        __shared__ float rxs[4], rys[4];
        const int w = tid >> 6, lane = tid & 63;
        if (lane == 0) { rxs[w] = sx; rys[w] = sy; }
        __syncthreads();
        if (tid == 0) {
            float* meanws = (float*)(ws + WS_MEAN);
            meanws[b * 2 + 0] = (rxs[0] + rxs[1] + rxs[2] + rxs[3]) * (1.f / NA);
            meanws[b * 2 + 1] = (rys[0] + rys[1] + rys[2] + rys[3]) * (1.f / NA);
            out[b] = (float)NPAIR * pb2[0] + (float)NA * ab2[0];
        }
        return;
    }

    // ---- weight fragment packing ----
    _Float16* w0p = (_Float16*)(ws + WS_W0P);
    _Float16* w0a = (_Float16*)(ws + WS_W0A);
    _Float16* w1p = (_Float16*)(ws + WS_W1P);
    _Float16* w1a = (_Float16*)(ws + WS_W1A);

    for (int idx = tid; idx < 2048; idx += 256) {
        const int j = idx & 7, lane = (idx >> 3) & 63, nt = idx >> 9;
        const int k = ((lane >> 4) << 3) + j;
        const int col = nt * 16 + (lane & 15);
        float vp = 0.f, va = 0.f;
        if (k < 5) {
            vp = pW0[k * 64 + col];
            va = aW0[k * 64 + col];
        } else if (k >= 6 && k <= 9) {
            const int s = k - 6;
            float accp = 0.f, acca = 0.f;
#pragma unroll
            for (int e = 0; e < 16; e++) {
                float em = embed[s * 16 + e];
                accp += em * pW0[(5 + e) * 64 + col];
                acca += em * aW0[(5 + e) * 64 + col];
            }
            vp = accp; va = acca;
        } else if (k >= 10 && k <= 13) {
            const int s = k - 10;
            float accp = 0.f;
#pragma unroll
            for (int e = 0; e < 16; e++)
                accp += embed[s * 16 + e] * pW0[(21 + e) * 64 + col];
            vp = accp; va = 0.f;
        }
        w0p[idx] = (_Float16)vp;
        w0a[idx] = (_Float16)va;
    }
    for (int idx = tid; idx < 4096; idx += 256) {
        const int j = idx & 7, lane = (idx >> 3) & 63;
        const int ks = (idx >> 9) & 1, nt = idx >> 10;
        const int k = ks * 32 + ((lane >> 4) << 3) + j;
        const int col = nt * 16 + (lane & 15);
        w1p[idx] = (_Float16)pW1[k * 64 + col];
        w1a[idx] = (_Float16)aW1[k * 64 + col];
    }
}

// ---------------------------------------------------------------------------
// fused pair+atom MLP. 128-thread blocks (2 waves), 16 KB LDS -> 10 blocks/CU.
// bx < 1023: pair tiles {bx + 1023*t, t=0..3} of 128 pairs each (exact).
// bx 1023/1024: atom tiles, 4 x 128 atoms each. Wave-private pipelines.
// ---------------------------------------------------------------------------
__global__ __launch_bounds__(128, 4) void mlp_kernel(
    const float* __restrict__ positions,
    const int*   __restrict__ species,
    const float* __restrict__ efield,
    const float* __restrict__ ab0, const float* __restrict__ ab1,
    const float* __restrict__ aW2,
    const float* __restrict__ pb0, const float* __restrict__ pb1,
    const float* __restrict__ pW2,
    const char*  __restrict__ ws,
    float* __restrict__ out)
{
    const int b    = blockIdx.y;
    const int bx   = blockIdx.x;
    const bool is_atom = (bx >= PAIR_BLOCKS);
    const int tid  = threadIdx.x;
    const int lane = tid & 63;
    const int wv   = tid >> 6;
    const int n16  = lane & 15;
    const int quad = lane >> 4;

    // 2 waves x 64 rows x 64 halves, XOR-swizzled chunks. 16384 B exactly.
    __shared__ __attribute__((aligned(16))) _Float16 Hbuf[2][64 * 64];
    _Float16* rows = Hbuf[wv];

    // ---- block-wide weight fragments (coalesced, once per block) ----
    const _Float16* w0w = (const _Float16*)(ws + (is_atom ? WS_W0A : WS_W0P));
    const _Float16* w1w = (const _Float16*)(ws + (is_atom ? WS_W1A : WS_W1P));
    half8 w0f[4], w1f[4][2];
#pragma unroll
    for (int nt = 0; nt < 4; nt++)
        w0f[nt] = *(const half8*)(w0w + (nt * 64 + lane) * 8);
#pragma unroll
    for (int nt = 0; nt < 4; nt++)
#pragma unroll
        for (int ks = 0; ks < 2; ks++)
            w1f[nt][ks] = *(const half8*)(w1w + ((nt * 2 + ks) * 64 + lane) * 8);

    const float* B0 = is_atom ? ab0 : pb0;
    const float* B1 = is_atom ? ab1 : pb1;
    const float* W2 = is_atom ? aW2 : pW2;
    float b0v[4], b1v[4], w2v[4];
#pragma unroll
    for (int nt = 0; nt < 4; nt++) {
        b0v[nt] = B0[nt * 16 + n16];
        b1v[nt] = B1[nt * 16 + n16];
        w2v[nt] = W2[nt * 16 + n16];
    }

    const float Ex = efield[b * 2 + 0];
    const float Ey = efield[b * 2 + 1];
    const float enorm = sqrtf(Ex * Ex + Ey * Ey);
    const float* meanws = (const float*)(ws + WS_MEAN);

    float energy = 0.f;
#pragma unroll 1
    for (int t = 0; t < 4; ++t) {
        // ---- build feature row (13 live halves of K=32) ----
        float f0, f1, f2, f3;
        uint64_t ohi, ohj;
        if (!is_atom) {
            const int tile = bx + t * PAIR_BLOCKS;
            const int p = tile * 128 + tid;
            float Df = (float)(2047 * 2047 - 8 * p);
            int i = (int)((2047.0f - sqrtf(Df)) * 0.5f);
            i = i < 0 ? 0 : (i > 1022 ? 1022 : i);
            while (i * (2047 - i) / 2 > p) --i;
            while ((i + 1) * (2046 - i) / 2 <= p) ++i;
            const int j = p - i * (2047 - i) / 2 + i + 1;
            const float2* pos = (const float2*)positions + b * NA;
            float2 pi = pos[i], pj = pos[j];
            f0 = pi.x - pj.x; f1 = pi.y - pj.y;           // mean cancels
            f2 = sqrtf(f0 * f0 + f1 * f1);
            float inv = __builtin_amdgcn_rcpf(fmaxf(f2, 1e-12f));
            f3 = (Ex * f0 + Ey * f1) * inv;
            ohi = 0x3C00ull << (species[b * NA + i] * 16);
            ohj = 0x3C00ull << (species[b * NA + j] * 16);
        } else {
            const int n = ((bx - PAIR_BLOCKS) * 4 + t) * 128 + tid;
            float2 pn = ((const float2*)positions)[b * NA + n];
            f0 = pn.x - meanws[b * 2 + 0];
            f1 = pn.y - meanws[b * 2 + 1];
            f2 = Ex; f3 = Ey;
            ohi = 0x3C00ull << (species[b * NA + n] * 16);
            ohj = 0;
        }
        // halves: 0..4 = f0..f4(enorm), 5 = 0, 6..9 = oh_i, 10..13 = oh_j
        int4 lo, hi;
        lo.x = (int)pkf16(f0, f1);
        lo.y = (int)pkf16(f2, f3);
        lo.z = (int)pkf16(enorm, 0.f);
        lo.w = (int)(uint32_t)ohi;
        hi.x = (int)(uint32_t)(ohi >> 32);
        hi.y = (int)(uint32_t)ohj;
        hi.z = (int)(uint32_t)(ohj >> 32);
        hi.w = 0;
        *(int4*)(rows + lds_off(lane, 0)) = lo;
        *(int4*)(rows + lds_off(lane, 1)) = hi;
        *(int4*)(rows + lds_off(lane, 2)) = make_int4(0, 0, 0, 0);  // K pad
        *(int4*)(rows + lds_off(lane, 3)) = make_int4(0, 0, 0, 0);

        // ---- 4 m-tiles: L0 (K=32) -> silu -> H -> L1 (K=64) -> energy ----
#pragma unroll
        for (int mt = 0; mt < 4; mt++) {
            half8 a = *(const half8*)(rows + lds_off(mt * 16 + n16, quad));

            float4v acc[4];
#pragma unroll
            for (int nt = 0; nt < 4; nt++) {
                float4v c = {b0v[nt], b0v[nt], b0v[nt], b0v[nt]};
                acc[nt] = __builtin_amdgcn_mfma_f32_16x16x32_f16(a, w0f[nt], c, 0, 0, 0);
            }
            // C layout: row = quad*4 + r, col = nt*16 + n16
#pragma unroll
            for (int nt = 0; nt < 4; nt++)
#pragma unroll
                for (int r = 0; r < 4; r++)
                    rows[lds_off(mt * 16 + quad * 4 + r, 2 * nt + (n16 >> 3)) + (n16 & 7)] =
                        (_Float16)silu_f(acc[nt][r]);

            half8 h0 = *(const half8*)(rows + lds_off(mt * 16 + n16, quad));
            half8 h1 = *(const half8*)(rows + lds_off(mt * 16 + n16, 4 + quad));
            float4v acc2[4];
#pragma unroll
            for (int nt = 0; nt < 4; nt++) {
                float4v c = {b1v[nt], b1v[nt], b1v[nt], b1v[nt]};
                c = __builtin_amdgcn_mfma_f32_16x16x32_f16(h0, w1f[nt][0], c, 0, 0, 0);
                c = __builtin_amdgcn_mfma_f32_16x16x32_f16(h1, w1f[nt][1], c, 0, 0, 0);
                acc2[nt] = c;
            }
#pragma unroll
            for (int nt = 0; nt < 4; nt++)
#pragma unroll
                for (int r = 0; r < 4; r++)
                    energy += silu_f(acc2[nt][r]) * w2v[nt];
        }
    }

    // ---- block reduction (reuse LDS) -> one atomicAdd per block ----
#pragma unroll
    for (int off = 32; off > 0; off >>= 1)
        energy += __shfl_down(energy, off);
    float* red = (float*)&Hbuf[0][0];
    if (lane == 0) red[wv] = energy;
    __syncthreads();
    if (tid == 0)
        atomicAdd(&out[b], red[0] + red[1]);
}

// ---------------------------------------------------------------------------
extern "C" void kernel_launch(void* const* d_in, const int* in_sizes, int n_in,
                              void* d_out, int out_size, void* d_ws, size_t ws_size,
                              hipStream_t stream) {
    const float* positions = (const float*)d_in[0];
    const int*   species   = (const int*)  d_in[1];
    const float* efield    = (const float*)d_in[2];
    const float* embed     = (const float*)d_in[3];
    const float* aW0 = (const float*)d_in[4];
    const float* ab0 = (const float*)d_in[5];
    const float* aW1 = (const float*)d_in[6];
    const float* ab1 = (const float*)d_in[7];
    const float* aW2 = (const float*)d_in[8];
    const float* ab2 = (const float*)d_in[9];
    const float* pW0 = (const float*)d_in[10];
    const float* pb0 = (const float*)d_in[11];
    const float* pW1 = (const float*)d_in[12];
    const float* pb1 = (const float*)d_in[13];
    const float* pW2 = (const float*)d_in[14];
    const float* pb2 = (const float*)d_in[15];
    float* outp = (float*)d_out;
    char*  ws   = (char*)d_ws;

    prep_kernel<<<dim3(5), dim3(256), 0, stream>>>(
        positions, embed, aW0, aW1, ab2, pW0, pW1, pb2, ws, outp);
    mlp_kernel<<<dim3(GRID_X, NBATCH), dim3(128), 0, stream>>>(
        positions, species, efield,
        ab0, ab1, aW2, pb0, pb1, pW2,
        ws, outp);
}

// Round 4
// 215.942 us; speedup vs baseline: 1.3095x; 1.3095x over previous
//
#include <hip/hip_runtime.h>

#define NA 1024
#define NBATCH 4
#define NPAIR 523776           // NA*(NA-1)/2
#define PAIR_BLOCKS 1023       // each does 4 tiles of 128 pairs (exact cover)
#define GRID_X 1025            // + 2 atom blocks (each 4 tiles of 128 atoms)

// ws layout (byte offsets)
#define WS_MEAN 0              // 8 floats (per-batch mean x,y)
#define WS_W0P  64             // 2048 halves: pair W0eff A-frags (hidden-major)
#define WS_W0A  4160           // 2048 halves: atom W0eff A-frags
#define WS_W1P  8256           // 4096 halves: pair W1 row-permuted B-frags
#define WS_W1A  16448          // 4096 halves: atom W1 row-permuted B-frags

typedef _Float16 half8 __attribute__((ext_vector_type(8)));
typedef float float4v __attribute__((ext_vector_type(4)));

#define FSTRIDE 40             // feature row stride in halves (80 B: 16B-aligned,
                               // 20L%32 bank spread -> conflict-free b128)

__device__ __forceinline__ float silu_f(float x) {
    return x * __builtin_amdgcn_rcpf(1.0f + __expf(-x));
}

__device__ __forceinline__ uint32_t pkf16(float a, float b) {
    union { _Float16 h[2]; uint32_t u; } x;
    x.h[0] = (_Float16)a; x.h[1] = (_Float16)b;   // RTNE
    return x.u;
}

// ---------------------------------------------------------------------------
// prep: blocks 0..3 -> per-batch mean + out[b] init; block 4 -> weight packing.
// W0eff rows (K=14 live of 32): 0..4 = raw feature rows, 5 = 0,
// 6..9 = one-hot(i) rows (embed@W0 folded), 10..13 = one-hot(j) (pair only),
// 14..31 = 0. Frag order: [(nt*64+lane)*8+j] = W0eff[(lane>>4)*8+j][nt*16+(lane&15)]
// (used as the A operand of the swapped L0: A[m=n16][k=quad*8+j]).
// W1 frags are ROW-PERMUTED: hidden unit at L1-k-slot k is
// n_phys(k) = (2*((k>>2)&1) + (k>>5))*16 + ((k>>3)&3)*4 + (k&3),
// matching the register layout of silu(L0) h-fragments (no LDS round-trip).
// ---------------------------------------------------------------------------
__global__ void prep_kernel(const float* __restrict__ positions,
                            const float* __restrict__ embed,
                            const float* __restrict__ aW0,
                            const float* __restrict__ aW1,
                            const float* __restrict__ ab2,
                            const float* __restrict__ pW0,
                            const float* __restrict__ pW1,
                            const float* __restrict__ pb2,
                            char* __restrict__ ws,
                            float* __restrict__ out) {
    const int tid = threadIdx.x;
    if (blockIdx.x < 4) {
        const int b = blockIdx.x;
        const float2* pos = (const float2*)positions + b * NA;
        float sx = 0.f, sy = 0.f;
        for (int t = tid; t < NA; t += 256) {
            float2 p = pos[t];
            sx += p.x; sy += p.y;
        }
#pragma unroll
        for (int off = 32; off > 0; off >>= 1) {
            sx += __shfl_down(sx, off);
            sy += __shfl_down(sy, off);
        }
        __shared__ float rxs[4], rys[4];
        const int w = tid >> 6, lane = tid & 63;
        if (lane == 0) { rxs[w] = sx; rys[w] = sy; }
        __syncthreads();
        if (tid == 0) {
            float* meanws = (float*)(ws + WS_MEAN);
            meanws[b * 2 + 0] = (rxs[0] + rxs[1] + rxs[2] + rxs[3]) * (1.f / NA);
            meanws[b * 2 + 1] = (rys[0] + rys[1] + rys[2] + rys[3]) * (1.f / NA);
            out[b] = (float)NPAIR * pb2[0] + (float)NA * ab2[0];
        }
        return;
    }

    _Float16* w0p = (_Float16*)(ws + WS_W0P);
    _Float16* w0a = (_Float16*)(ws + WS_W0A);
    _Float16* w1p = (_Float16*)(ws + WS_W1P);
    _Float16* w1a = (_Float16*)(ws + WS_W1A);

    for (int idx = tid; idx < 2048; idx += 256) {
        const int j = idx & 7, lane = (idx >> 3) & 63, nt = idx >> 9;
        const int k = ((lane >> 4) << 3) + j;
        const int col = nt * 16 + (lane & 15);
        float vp = 0.f, va = 0.f;
        if (k < 5) {
            vp = pW0[k * 64 + col];
            va = aW0[k * 64 + col];
        } else if (k >= 6 && k <= 9) {
            const int s = k - 6;
            float accp = 0.f, acca = 0.f;
#pragma unroll
            for (int e = 0; e < 16; e++) {
                float em = embed[s * 16 + e];
                accp += em * pW0[(5 + e) * 64 + col];
                acca += em * aW0[(5 + e) * 64 + col];
            }
            vp = accp; va = acca;
        } else if (k >= 10 && k <= 13) {
            const int s = k - 10;
            float accp = 0.f;
#pragma unroll
            for (int e = 0; e < 16; e++)
                accp += embed[s * 16 + e] * pW0[(21 + e) * 64 + col];
            vp = accp; va = 0.f;
        }
        w0p[idx] = (_Float16)vp;
        w0a[idx] = (_Float16)va;
    }
    for (int idx = tid; idx < 4096; idx += 256) {
        const int j = idx & 7, lane = (idx >> 3) & 63;
        const int ks = (idx >> 9) & 1, nt2 = idx >> 10;
        const int k = ks * 32 + ((lane >> 4) << 3) + j;
        const int r = k & 3, hj = (k >> 2) & 1, qd = (k >> 3) & 3, kss = k >> 5;
        const int nphys = (2 * hj + kss) * 16 + qd * 4 + r;
        const int col = nt2 * 16 + (lane & 15);
        w1p[idx] = (_Float16)pW1[nphys * 64 + col];
        w1a[idx] = (_Float16)aW1[nphys * 64 + col];
    }
}

// ---------------------------------------------------------------------------
// fused pair+atom MLP. 128-thread blocks (2 waves), ~10 KB LDS.
// Swapped-operand L0 (weights = A operand) => each lane's 16 L0 outputs all
// belong to its own row n16; silu packs them in-register into the exact L1
// A-fragments (hidden dim re-ordered via the W1 row permutation in prep).
// Only features go through LDS. All LDS addressing affine (no spill).
// ---------------------------------------------------------------------------
__global__ __launch_bounds__(128, 4) void mlp_kernel(
    const float* __restrict__ positions,
    const int*   __restrict__ species,
    const float* __restrict__ efield,
    const float* __restrict__ ab0, const float* __restrict__ ab1,
    const float* __restrict__ aW2,
    const float* __restrict__ pb0, const float* __restrict__ pb1,
    const float* __restrict__ pW2,
    const char*  __restrict__ ws,
    float* __restrict__ out)
{
    const int b    = blockIdx.y;
    const int bx   = blockIdx.x;
    const bool is_atom = (bx >= PAIR_BLOCKS);
    const int tid  = threadIdx.x;
    const int lane = tid & 63;
    const int wv   = tid >> 6;
    const int n16  = lane & 15;
    const int quad = lane >> 4;

    // 2 waves x 64 feature rows x FSTRIDE halves (wave-private halves)
    __shared__ __attribute__((aligned(16))) _Float16 Fbuf[2][64 * FSTRIDE];
    _Float16* rows = Fbuf[wv];

    // ---- weight fragments (coalesced, once per block) ----
    const _Float16* w0w = (const _Float16*)(ws + (is_atom ? WS_W0A : WS_W0P));
    const _Float16* w1w = (const _Float16*)(ws + (is_atom ? WS_W1A : WS_W1P));
    half8 w0f[4], w1f[4][2];
#pragma unroll
    for (int nt = 0; nt < 4; nt++)
        w0f[nt] = *(const half8*)(w0w + (nt * 64 + lane) * 8);
#pragma unroll
    for (int nt = 0; nt < 4; nt++)
#pragma unroll
        for (int ks = 0; ks < 2; ks++)
            w1f[nt][ks] = *(const half8*)(w1w + ((nt * 2 + ks) * 64 + lane) * 8);

    const float* B0 = is_atom ? ab0 : pb0;
    const float* B1 = is_atom ? ab1 : pb1;
    const float* W2 = is_atom ? aW2 : pW2;
    // L0-swapped C rows are hidden units: bias per (nt, quad, r)
    float4v b0v[4];
    float b1v[4], w2v[4];
#pragma unroll
    for (int nt = 0; nt < 4; nt++) {
#pragma unroll
        for (int r = 0; r < 4; r++)
            b0v[nt][r] = B0[nt * 16 + quad * 4 + r];
        b1v[nt] = B1[nt * 16 + n16];
        w2v[nt] = W2[nt * 16 + n16];
    }

    const float Ex = efield[b * 2 + 0];
    const float Ey = efield[b * 2 + 1];
    const float enorm = sqrtf(Ex * Ex + Ey * Ey);
    const float* meanws = (const float*)(ws + WS_MEAN);

    // zero the K-pad halves 16..31 once (never rewritten)
    *(int4*)(rows + lane * FSTRIDE + 16) = make_int4(0, 0, 0, 0);
    *(int4*)(rows + lane * FSTRIDE + 24) = make_int4(0, 0, 0, 0);

    float energy = 0.f;
#pragma unroll 1
    for (int t = 0; t < 4; ++t) {
        // ---- build feature row (14 live halves of K=32) ----
        float f0, f1, f2, f3;
        uint64_t ohi, ohj;
        if (!is_atom) {
            const int tile = bx + t * PAIR_BLOCKS;
            const int p = tile * 128 + tid;
            float Df = (float)(2047 * 2047 - 8 * p);
            int i = (int)((2047.0f - sqrtf(Df)) * 0.5f);
            i = i < 0 ? 0 : (i > 1022 ? 1022 : i);
            while (i * (2047 - i) / 2 > p) --i;
            while ((i + 1) * (2046 - i) / 2 <= p) ++i;
            const int j = p - i * (2047 - i) / 2 + i + 1;
            const float2* pos = (const float2*)positions + b * NA;
            float2 pi = pos[i], pj = pos[j];
            f0 = pi.x - pj.x; f1 = pi.y - pj.y;           // mean cancels
            f2 = sqrtf(f0 * f0 + f1 * f1);
            float inv = __builtin_amdgcn_rcpf(fmaxf(f2, 1e-12f));
            f3 = (Ex * f0 + Ey * f1) * inv;
            ohi = 0x3C00ull << (species[b * NA + i] * 16);
            ohj = 0x3C00ull << (species[b * NA + j] * 16);
        } else {
            const int n = ((bx - PAIR_BLOCKS) * 4 + t) * 128 + tid;
            float2 pn = ((const float2*)positions)[b * NA + n];
            f0 = pn.x - meanws[b * 2 + 0];
            f1 = pn.y - meanws[b * 2 + 1];
            f2 = Ex; f3 = Ey;
            ohi = 0x3C00ull << (species[b * NA + n] * 16);
            ohj = 0;
        }
        // halves: 0..4 = f0..f4(enorm), 5 = 0, 6..9 = oh_i, 10..13 = oh_j, 14..15 = 0
        int4 lo, hi;
        lo.x = (int)pkf16(f0, f1);
        lo.y = (int)pkf16(f2, f3);
        lo.z = (int)pkf16(enorm, 0.f);
        lo.w = (int)(uint32_t)ohi;
        hi.x = (int)(uint32_t)(ohi >> 32);
        hi.y = (int)(uint32_t)ohj;
        hi.z = (int)(uint32_t)(ohj >> 32);
        hi.w = 0;
        *(int4*)(rows + lane * FSTRIDE) = lo;
        *(int4*)(rows + lane * FSTRIDE + 8) = hi;

        // ---- 4 row-groups of 16 rows each ----
#pragma unroll 1
        for (int g = 0; g < 4; ++g) {
            // feature B-frag: B[k=quad*8+j][n=n16] = feat[g*16+n16][quad*8+j]
            half8 bf = *(const half8*)(rows + (g * 16 + n16) * FSTRIDE + quad * 8);

            // L0 swapped: D1 = W0eff^T x feat^T ; lane holds, for tile nt,
            // h[row n16][hidden nt*16+quad*4+r] in element r
            float4v a1[4];
#pragma unroll
            for (int nt = 0; nt < 4; nt++)
                a1[nt] = __builtin_amdgcn_mfma_f32_16x16x32_f16(w0f[nt], bf, b0v[nt], 0, 0, 0);

            // silu -> in-register L1 A-frags (hidden order matches W1 perm)
            half8 h0, h1;
#pragma unroll
            for (int r = 0; r < 4; r++) {
                h0[r]     = (_Float16)silu_f(a1[0][r]);
                h1[r]     = (_Float16)silu_f(a1[1][r]);
                h0[4 + r] = (_Float16)silu_f(a1[2][r]);
                h1[4 + r] = (_Float16)silu_f(a1[3][r]);
            }

            // L1 standard: A = h-frags (rows of this group), B = permuted W1
            float4v a2[4];
#pragma unroll
            for (int nt = 0; nt < 4; nt++) {
                float4v c = {b1v[nt], b1v[nt], b1v[nt], b1v[nt]};
                c = __builtin_amdgcn_mfma_f32_16x16x32_f16(h0, w1f[nt][0], c, 0, 0, 0);
                c = __builtin_amdgcn_mfma_f32_16x16x32_f16(h1, w1f[nt][1], c, 0, 0, 0);
                a2[nt] = c;
            }
            // L2: energy += silu(h2) . w2 (C cols = hidden n16-indexed)
#pragma unroll
            for (int nt = 0; nt < 4; nt++)
#pragma unroll
                for (int r = 0; r < 4; r++)
                    energy += silu_f(a2[nt][r]) * w2v[nt];
        }
    }

    // ---- wave reduction -> one atomicAdd per wave ----
#pragma unroll
    for (int off = 32; off > 0; off >>= 1)
        energy += __shfl_down(energy, off);
    if (lane == 0)
        atomicAdd(&out[b], energy);
}

// ---------------------------------------------------------------------------
extern "C" void kernel_launch(void* const* d_in, const int* in_sizes, int n_in,
                              void* d_out, int out_size, void* d_ws, size_t ws_size,
                              hipStream_t stream) {
    const float* positions = (const float*)d_in[0];
    const int*   species   = (const int*)  d_in[1];
    const float* efield    = (const float*)d_in[2];
    const float* embed     = (const float*)d_in[3];
    const float* aW0 = (const float*)d_in[4];
    const float* ab0 = (const float*)d_in[5];
    const float* aW1 = (const float*)d_in[6];
    const float* ab1 = (const float*)d_in[7];
    const float* aW2 = (const float*)d_in[8];
    const float* ab2 = (const float*)d_in[9];
    const float* pW0 = (const float*)d_in[10];
    const float* pb0 = (const float*)d_in[11];
    const float* pW1 = (const float*)d_in[12];
    const float* pb1 = (const float*)d_in[13];
    const float* pW2 = (const float*)d_in[14];
    const float* pb2 = (const float*)d_in[15];
    float* outp = (float*)d_out;
    char*  ws   = (char*)d_ws;

    prep_kernel<<<dim3(5), dim3(256), 0, stream>>>(
        positions, embed, aW0, aW1, ab2, pW0, pW1, pb2, ws, outp);
    mlp_kernel<<<dim3(GRID_X, NBATCH), dim3(128), 0, stream>>>(
        positions, species, efield,
        ab0, ab1, aW2, pb0, pb1, pW2,
        ws, outp);
}

// Round 5
// 213.212 us; speedup vs baseline: 1.3262x; 1.0128x over previous
//
#include <hip/hip_runtime.h>

#define NA 1024
#define NBATCH 4
#define NPAIR 523776           // NA*(NA-1)/2
#define PAIR_BLOCKS 1023       // each does 4 tiles of 128 pairs (exact cover)
#define GRID_X 1025            // + 2 atom blocks (each 4 tiles of 128 atoms)

// ws layout (byte offsets)
#define WS_MEAN 0              // 8 floats (per-batch mean x,y)
#define WS_W0P  64             // 2048 halves: pair W0eff A-frags (hidden-major)
#define WS_W0A  4160           // 2048 halves: atom W0eff A-frags
#define WS_W1P  8256           // 4096 halves: pair W1 row-permuted B-frags
#define WS_W1A  16448          // 4096 halves: atom W1 row-permuted B-frags

typedef _Float16 half8 __attribute__((ext_vector_type(8)));
typedef float float4v __attribute__((ext_vector_type(4)));

#define FSTRIDE 40             // feature row stride in halves (80 B: 16B-aligned,
                               // conflict-free b128)

__device__ __forceinline__ float silu_f(float x) {
    return x * __builtin_amdgcn_rcpf(1.0f + __expf(-x));
}

__device__ __forceinline__ uint32_t pkf16(float a, float b) {
    union { _Float16 h[2]; uint32_t u; } x;
    x.h[0] = (_Float16)a; x.h[1] = (_Float16)b;   // RTNE
    return x.u;
}

// ---------------------------------------------------------------------------
// prep (28 blocks x 256): blocks 0..3 -> per-batch mean + out[b] init;
// blocks 4..11 -> W0eff frag packing (1 item/thread);
// blocks 12..27 -> W1 permuted frag packing (1 item/thread).
// W0eff rows (K=14 live of 32): 0..4 raw features, 5 = 0, 6..9 one-hot(i)
// (embed@W0 folded), 10..13 one-hot(j) (pair only), 14..31 = 0.
// Frag order: [(nt*64+lane)*8+j] = W0eff[(lane>>4)*8+j][nt*16+(lane&15)]
// (A operand of swapped L0). W1 frags ROW-PERMUTED: L1-k-slot k holds hidden
// unit n_phys(k) = (2*((k>>2)&1) + (k>>5))*16 + ((k>>3)&3)*4 + (k&3), matching
// the register layout of silu(L0) h-fragments (no LDS round-trip).
// ---------------------------------------------------------------------------
__global__ void prep_kernel(const float* __restrict__ positions,
                            const float* __restrict__ embed,
                            const float* __restrict__ aW0,
                            const float* __restrict__ aW1,
                            const float* __restrict__ ab2,
                            const float* __restrict__ pW0,
                            const float* __restrict__ pW1,
                            const float* __restrict__ pb2,
                            char* __restrict__ ws,
                            float* __restrict__ out) {
    const int tid = threadIdx.x;
    const int bxp = blockIdx.x;
    if (bxp < 4) {
        const int b = bxp;
        const float2* pos = (const float2*)positions + b * NA;
        float sx = 0.f, sy = 0.f;
        for (int t = tid; t < NA; t += 256) {
            float2 p = pos[t];
            sx += p.x; sy += p.y;
        }
#pragma unroll
        for (int off = 32; off > 0; off >>= 1) {
            sx += __shfl_down(sx, off);
            sy += __shfl_down(sy, off);
        }
        __shared__ float rxs[4], rys[4];
        const int w = tid >> 6, lane = tid & 63;
        if (lane == 0) { rxs[w] = sx; rys[w] = sy; }
        __syncthreads();
        if (tid == 0) {
            float* meanws = (float*)(ws + WS_MEAN);
            meanws[b * 2 + 0] = (rxs[0] + rxs[1] + rxs[2] + rxs[3]) * (1.f / NA);
            meanws[b * 2 + 1] = (rys[0] + rys[1] + rys[2] + rys[3]) * (1.f / NA);
            out[b] = (float)NPAIR * pb2[0] + (float)NA * ab2[0];
        }
        return;
    }

    _Float16* w0p = (_Float16*)(ws + WS_W0P);
    _Float16* w0a = (_Float16*)(ws + WS_W0A);
    _Float16* w1p = (_Float16*)(ws + WS_W1P);
    _Float16* w1a = (_Float16*)(ws + WS_W1A);

    if (bxp < 12) {
        const int idx = (bxp - 4) * 256 + tid;           // [0, 2048)
        const int j = idx & 7, lane = (idx >> 3) & 63, nt = idx >> 9;
        const int k = ((lane >> 4) << 3) + j;
        const int col = nt * 16 + (lane & 15);
        float vp = 0.f, va = 0.f;
        if (k < 5) {
            vp = pW0[k * 64 + col];
            va = aW0[k * 64 + col];
        } else if (k >= 6 && k <= 9) {
            const int s = k - 6;
            float accp = 0.f, acca = 0.f;
#pragma unroll
            for (int e = 0; e < 16; e++) {
                float em = embed[s * 16 + e];
                accp += em * pW0[(5 + e) * 64 + col];
                acca += em * aW0[(5 + e) * 64 + col];
            }
            vp = accp; va = acca;
        } else if (k >= 10 && k <= 13) {
            const int s = k - 10;
            float accp = 0.f;
#pragma unroll
            for (int e = 0; e < 16; e++)
                accp += embed[s * 16 + e] * pW0[(21 + e) * 64 + col];
            vp = accp; va = 0.f;
        }
        w0p[idx] = (_Float16)vp;
        w0a[idx] = (_Float16)va;
    } else {
        const int idx = (bxp - 12) * 256 + tid;          // [0, 4096)
        const int j = idx & 7, lane = (idx >> 3) & 63;
        const int ks = (idx >> 9) & 1, nt2 = idx >> 10;
        const int k = ks * 32 + ((lane >> 4) << 3) + j;
        const int r = k & 3, hj = (k >> 2) & 1, qd = (k >> 3) & 3, kss = k >> 5;
        const int nphys = (2 * hj + kss) * 16 + qd * 4 + r;
        const int col = nt2 * 16 + (lane & 15);
        w1p[idx] = (_Float16)pW1[nphys * 64 + col];
        w1a[idx] = (_Float16)aW1[nphys * 64 + col];
    }
}

// ---------------------------------------------------------------------------
// fused pair+atom MLP. 128-thread blocks (2 waves), ~10 KB LDS.
// Swapped-operand L0 (weights = A) => lane's 16 L0 outputs belong to its own
// row n16; silu packs in-register into L1 A-frags (W1 row-permuted in prep).
// g-loop FULLY UNROLLED: 4 independent MFMA->silu->MFMA chains in flight
// (R4's unroll-1 serialized the chain -> 51% VALUBusy; this is the fix).
// ---------------------------------------------------------------------------
__global__ __launch_bounds__(128, 4) void mlp_kernel(
    const float* __restrict__ positions,
    const int*   __restrict__ species,
    const float* __restrict__ efield,
    const float* __restrict__ ab0, const float* __restrict__ ab1,
    const float* __restrict__ aW2,
    const float* __restrict__ pb0, const float* __restrict__ pb1,
    const float* __restrict__ pW2,
    const char*  __restrict__ ws,
    float* __restrict__ out)
{
    const int b    = blockIdx.y;
    const int bx   = blockIdx.x;
    const bool is_atom = (bx >= PAIR_BLOCKS);
    const int tid  = threadIdx.x;
    const int lane = tid & 63;
    const int wv   = tid >> 6;
    const int n16  = lane & 15;
    const int quad = lane >> 4;

    __shared__ __attribute__((aligned(16))) _Float16 Fbuf[2][64 * FSTRIDE];
    _Float16* rows = Fbuf[wv];

    // ---- weight fragments (coalesced, once per block) ----
    const _Float16* w0w = (const _Float16*)(ws + (is_atom ? WS_W0A : WS_W0P));
    const _Float16* w1w = (const _Float16*)(ws + (is_atom ? WS_W1A : WS_W1P));
    half8 w0f[4], w1f[4][2];
#pragma unroll
    for (int nt = 0; nt < 4; nt++)
        w0f[nt] = *(const half8*)(w0w + (nt * 64 + lane) * 8);
#pragma unroll
    for (int nt = 0; nt < 4; nt++)
#pragma unroll
        for (int ks = 0; ks < 2; ks++)
            w1f[nt][ks] = *(const half8*)(w1w + ((nt * 2 + ks) * 64 + lane) * 8);

    const float* B0 = is_atom ? ab0 : pb0;
    const float* B1 = is_atom ? ab1 : pb1;
    const float* W2 = is_atom ? aW2 : pW2;
    // L0-swapped C rows are hidden units: bias per (nt, quad, r)
    float4v b0v[4];
    float b1v[4], w2v[4];
#pragma unroll
    for (int nt = 0; nt < 4; nt++) {
#pragma unroll
        for (int r = 0; r < 4; r++)
            b0v[nt][r] = B0[nt * 16 + quad * 4 + r];
        b1v[nt] = B1[nt * 16 + n16];
        w2v[nt] = W2[nt * 16 + n16];
    }

    const float Ex = efield[b * 2 + 0];
    const float Ey = efield[b * 2 + 1];
    const float enorm = sqrtf(Ex * Ex + Ey * Ey);
    const float* meanws = (const float*)(ws + WS_MEAN);

    // zero the K-pad halves 16..31 once (never rewritten)
    *(int4*)(rows + lane * FSTRIDE + 16) = make_int4(0, 0, 0, 0);
    *(int4*)(rows + lane * FSTRIDE + 24) = make_int4(0, 0, 0, 0);

    float energy = 0.f;
#pragma unroll 1
    for (int t = 0; t < 4; ++t) {
        // ---- build feature row (14 live halves of K=32) ----
        float f0, f1, f2, f3;
        uint64_t ohi, ohj;
        if (!is_atom) {
            const int tile = bx + t * PAIR_BLOCKS;
            const int p = tile * 128 + tid;
            float Df = (float)(2047 * 2047 - 8 * p);
            int i = (int)((2047.0f - sqrtf(Df)) * 0.5f);
            i = i < 0 ? 0 : (i > 1022 ? 1022 : i);
            while (i * (2047 - i) / 2 > p) --i;
            while ((i + 1) * (2046 - i) / 2 <= p) ++i;
            const int j = p - i * (2047 - i) / 2 + i + 1;
            const float2* pos = (const float2*)positions + b * NA;
            float2 pi = pos[i], pj = pos[j];
            f0 = pi.x - pj.x; f1 = pi.y - pj.y;           // mean cancels
            f2 = sqrtf(f0 * f0 + f1 * f1);
            float inv = __builtin_amdgcn_rcpf(fmaxf(f2, 1e-12f));
            f3 = (Ex * f0 + Ey * f1) * inv;
            ohi = 0x3C00ull << (species[b * NA + i] * 16);
            ohj = 0x3C00ull << (species[b * NA + j] * 16);
        } else {
            const int n = ((bx - PAIR_BLOCKS) * 4 + t) * 128 + tid;
            float2 pn = ((const float2*)positions)[b * NA + n];
            f0 = pn.x - meanws[b * 2 + 0];
            f1 = pn.y - meanws[b * 2 + 1];
            f2 = Ex; f3 = Ey;
            ohi = 0x3C00ull << (species[b * NA + n] * 16);
            ohj = 0;
        }
        // halves: 0..4 = f0..f4(enorm), 5 = 0, 6..9 = oh_i, 10..13 = oh_j
        int4 lo, hi;
        lo.x = (int)pkf16(f0, f1);
        lo.y = (int)pkf16(f2, f3);
        lo.z = (int)pkf16(enorm, 0.f);
        lo.w = (int)(uint32_t)ohi;
        hi.x = (int)(uint32_t)(ohi >> 32);
        hi.y = (int)(uint32_t)ohj;
        hi.z = (int)(uint32_t)(ohj >> 32);
        hi.w = 0;
        *(int4*)(rows + lane * FSTRIDE) = lo;
        *(int4*)(rows + lane * FSTRIDE + 8) = hi;

        // ---- 4 row-groups of 16 rows, FULLY UNROLLED for cross-chain ILP ----
#pragma unroll
        for (int g = 0; g < 4; ++g) {
            // feature B-frag: B[k=quad*8+j][n=n16] = feat[g*16+n16][quad*8+j]
            half8 bf = *(const half8*)(rows + (g * 16 + n16) * FSTRIDE + quad * 8);

            // L0 swapped: lane holds, for tile nt, h[row n16][nt*16+quad*4+r]
            float4v a1[4];
#pragma unroll
            for (int nt = 0; nt < 4; nt++)
                a1[nt] = __builtin_amdgcn_mfma_f32_16x16x32_f16(w0f[nt], bf, b0v[nt], 0, 0, 0);

            // silu -> in-register L1 A-frags (hidden order matches W1 perm)
            half8 h0, h1;
#pragma unroll
            for (int r = 0; r < 4; r++) {
                h0[r]     = (_Float16)silu_f(a1[0][r]);
                h1[r]     = (_Float16)silu_f(a1[1][r]);
                h0[4 + r] = (_Float16)silu_f(a1[2][r]);
                h1[4 + r] = (_Float16)silu_f(a1[3][r]);
            }

            // L1 standard: A = h-frags, B = permuted W1
            float4v a2[4];
#pragma unroll
            for (int nt = 0; nt < 4; nt++) {
                float4v c = {b1v[nt], b1v[nt], b1v[nt], b1v[nt]};
                c = __builtin_amdgcn_mfma_f32_16x16x32_f16(h0, w1f[nt][0], c, 0, 0, 0);
                c = __builtin_amdgcn_mfma_f32_16x16x32_f16(h1, w1f[nt][1], c, 0, 0, 0);
                a2[nt] = c;
            }
            // L2: energy += silu(h2) . w2
#pragma unroll
            for (int nt = 0; nt < 4; nt++)
#pragma unroll
                for (int r = 0; r < 4; r++)
                    energy += silu_f(a2[nt][r]) * w2v[nt];
        }
    }

    // ---- wave reduction -> one atomicAdd per wave ----
#pragma unroll
    for (int off = 32; off > 0; off >>= 1)
        energy += __shfl_down(energy, off);
    if (lane == 0)
        atomicAdd(&out[b], energy);
}

// ---------------------------------------------------------------------------
extern "C" void kernel_launch(void* const* d_in, const int* in_sizes, int n_in,
                              void* d_out, int out_size, void* d_ws, size_t ws_size,
                              hipStream_t stream) {
    const float* positions = (const float*)d_in[0];
    const int*   species   = (const int*)  d_in[1];
    const float* efield    = (const float*)d_in[2];
    const float* embed     = (const float*)d_in[3];
    const float* aW0 = (const float*)d_in[4];
    const float* ab0 = (const float*)d_in[5];
    const float* aW1 = (const float*)d_in[6];
    const float* ab1 = (const float*)d_in[7];
    const float* aW2 = (const float*)d_in[8];
    const float* ab2 = (const float*)d_in[9];
    const float* pW0 = (const float*)d_in[10];
    const float* pb0 = (const float*)d_in[11];
    const float* pW1 = (const float*)d_in[12];
    const float* pb1 = (const float*)d_in[13];
    const float* pW2 = (const float*)d_in[14];
    const float* pb2 = (const float*)d_in[15];
    float* outp = (float*)d_out;
    char*  ws   = (char*)d_ws;

    prep_kernel<<<dim3(28), dim3(256), 0, stream>>>(
        positions, embed, aW0, aW1, ab2, pW0, pW1, pb2, ws, outp);
    mlp_kernel<<<dim3(GRID_X, NBATCH), dim3(128), 0, stream>>>(
        positions, species, efield,
        ab0, ab1, aW2, pb0, pb1, pW2,
        ws, outp);
}

// Round 7
// 208.377 us; speedup vs baseline: 1.3570x; 1.0232x over previous
//
#include <hip/hip_runtime.h>

#define NA 1024
#define NBATCH 4
#define NPAIR 523776           // NA*(NA-1)/2
#define PAIR_BLOCKS 1023       // each does 4 tiles of 128 pairs (exact cover)
#define GRID_X 1025            // + 2 atom blocks (each 4 tiles of 128 atoms)

// ws layout (byte offsets)
#define WS_MEAN 0              // 8 floats (per-batch mean x,y)
#define WS_W0P  64             // 2048 halves: pair W0eff A-frags (hidden-major)
#define WS_W0A  4160           // 2048 halves: atom W0eff A-frags
#define WS_W1P  8256           // 4096 halves: pair W1 row-permuted B-frags
#define WS_W1A  16448          // 4096 halves: atom W1 row-permuted B-frags

typedef _Float16 half8 __attribute__((ext_vector_type(8)));
typedef __fp16 fp16x2 __attribute__((ext_vector_type(2)));   // pkrtz return type
typedef float float4v __attribute__((ext_vector_type(4)));

#define FSTRIDE 40             // feature row stride in halves (80 B)

__device__ __forceinline__ uint32_t pkf16(float a, float b) {
    union { _Float16 h[2]; uint32_t u; } x;
    x.h[0] = (_Float16)a; x.h[1] = (_Float16)b;   // RTNE
    return x.u;
}

// ---------------------------------------------------------------------------
// prep (28 blocks x 256): blocks 0..3 -> per-batch mean + out[b] init;
// blocks 4..11 -> W0eff frag packing; blocks 12..27 -> W1 permuted frags.
// W0eff rows (K=14 live of 32): 0..4 raw features, 5 = 0, 6..9 one-hot(i)
// (embed@W0 folded), 10..13 one-hot(j) (pair only), 14..31 = 0.
// Frag order: [(nt*64+lane)*8+j] = W0eff[(lane>>4)*8+j][nt*16+(lane&15)]
// (A operand of swapped L0). W1 frags ROW-PERMUTED: L1-k-slot k holds hidden
// unit n_phys(k) = (2*((k>>2)&1) + (k>>5))*16 + ((k>>3)&3)*4 + (k&3), matching
// the register layout of silu(L0) h-fragments (no LDS round-trip).
// ---------------------------------------------------------------------------
__global__ void prep_kernel(const float* __restrict__ positions,
                            const float* __restrict__ embed,
                            const float* __restrict__ aW0,
                            const float* __restrict__ aW1,
                            const float* __restrict__ ab2,
                            const float* __restrict__ pW0,
                            const float* __restrict__ pW1,
                            const float* __restrict__ pb2,
                            char* __restrict__ ws,
                            float* __restrict__ out) {
    const int tid = threadIdx.x;
    const int bxp = blockIdx.x;
    if (bxp < 4) {
        const int b = bxp;
        const float2* pos = (const float2*)positions + b * NA;
        float sx = 0.f, sy = 0.f;
        for (int t = tid; t < NA; t += 256) {
            float2 p = pos[t];
            sx += p.x; sy += p.y;
        }
#pragma unroll
        for (int off = 32; off > 0; off >>= 1) {
            sx += __shfl_down(sx, off);
            sy += __shfl_down(sy, off);
        }
        __shared__ float rxs[4], rys[4];
        const int w = tid >> 6, lane = tid & 63;
        if (lane == 0) { rxs[w] = sx; rys[w] = sy; }
        __syncthreads();
        if (tid == 0) {
            float* meanws = (float*)(ws + WS_MEAN);
            meanws[b * 2 + 0] = (rxs[0] + rxs[1] + rxs[2] + rxs[3]) * (1.f / NA);
            meanws[b * 2 + 1] = (rys[0] + rys[1] + rys[2] + rys[3]) * (1.f / NA);
            out[b] = (float)NPAIR * pb2[0] + (float)NA * ab2[0];
        }
        return;
    }

    _Float16* w0p = (_Float16*)(ws + WS_W0P);
    _Float16* w0a = (_Float16*)(ws + WS_W0A);
    _Float16* w1p = (_Float16*)(ws + WS_W1P);
    _Float16* w1a = (_Float16*)(ws + WS_W1A);

    if (bxp < 12) {
        const int idx = (bxp - 4) * 256 + tid;           // [0, 2048)
        const int j = idx & 7, lane = (idx >> 3) & 63, nt = idx >> 9;
        const int k = ((lane >> 4) << 3) + j;
        const int col = nt * 16 + (lane & 15);
        float vp = 0.f, va = 0.f;
        if (k < 5) {
            vp = pW0[k * 64 + col];
            va = aW0[k * 64 + col];
        } else if (k >= 6 && k <= 9) {
            const int s = k - 6;
            float accp = 0.f, acca = 0.f;
#pragma unroll
            for (int e = 0; e < 16; e++) {
                float em = embed[s * 16 + e];
                accp += em * pW0[(5 + e) * 64 + col];
                acca += em * aW0[(5 + e) * 64 + col];
            }
            vp = accp; va = acca;
        } else if (k >= 10 && k <= 13) {
            const int s = k - 10;
            float accp = 0.f;
#pragma unroll
            for (int e = 0; e < 16; e++)
                accp += embed[s * 16 + e] * pW0[(21 + e) * 64 + col];
            vp = accp; va = 0.f;
        }
        w0p[idx] = (_Float16)vp;
        w0a[idx] = (_Float16)va;
    } else {
        const int idx = (bxp - 12) * 256 + tid;          // [0, 4096)
        const int j = idx & 7, lane = (idx >> 3) & 63;
        const int ks = (idx >> 9) & 1, nt2 = idx >> 10;
        const int k = ks * 32 + ((lane >> 4) << 3) + j;
        const int r = k & 3, hj = (k >> 2) & 1, qd = (k >> 3) & 3, kss = k >> 5;
        const int nphys = (2 * hj + kss) * 16 + qd * 4 + r;
        const int col = nt2 * 16 + (lane & 15);
        w1p[idx] = (_Float16)pW1[nphys * 64 + col];
        w1a[idx] = (_Float16)aW1[nphys * 64 + col];
    }
}

// ---------------------------------------------------------------------------
// fused pair+atom MLP. 128-thread blocks (2 waves), ~10 KB LDS.
// Swapped-operand L0 => silu packs in-register into L1 A-frags.
// silu is STAGED 16-WIDE (all exps, then all rcps, then muls) so the
// transcendental latency is hidden by issue of the 15 siblings — this is the
// R5 fix: at VGPR=64 the compiler serialized element-by-element and exposed
// ~100 stall cyc per silu. launch_bounds(128,3) raises the VGPR cap to ~170.
// ---------------------------------------------------------------------------
__global__ __launch_bounds__(128, 3) void mlp_kernel(
    const float* __restrict__ positions,
    const int*   __restrict__ species,
    const float* __restrict__ efield,
    const float* __restrict__ ab0, const float* __restrict__ ab1,
    const float* __restrict__ aW2,
    const float* __restrict__ pb0, const float* __restrict__ pb1,
    const float* __restrict__ pW2,
    const char*  __restrict__ ws,
    float* __restrict__ out)
{
    const int b    = blockIdx.y;
    const int bx   = blockIdx.x;
    const bool is_atom = (bx >= PAIR_BLOCKS);
    const int tid  = threadIdx.x;
    const int lane = tid & 63;
    const int wv   = tid >> 6;
    const int n16  = lane & 15;
    const int quad = lane >> 4;

    __shared__ __attribute__((aligned(16))) _Float16 Fbuf[2][64 * FSTRIDE];
    _Float16* rows = Fbuf[wv];

    // ---- weight fragments (coalesced, once per block) ----
    const _Float16* w0w = (const _Float16*)(ws + (is_atom ? WS_W0A : WS_W0P));
    const _Float16* w1w = (const _Float16*)(ws + (is_atom ? WS_W1A : WS_W1P));
    half8 w0f[4], w1f[4][2];
#pragma unroll
    for (int nt = 0; nt < 4; nt++)
        w0f[nt] = *(const half8*)(w0w + (nt * 64 + lane) * 8);
#pragma unroll
    for (int nt = 0; nt < 4; nt++)
#pragma unroll
        for (int ks = 0; ks < 2; ks++)
            w1f[nt][ks] = *(const half8*)(w1w + ((nt * 2 + ks) * 64 + lane) * 8);

    const float* B0 = is_atom ? ab0 : pb0;
    const float* B1 = is_atom ? ab1 : pb1;
    const float* W2 = is_atom ? aW2 : pW2;
    // L0-swapped C rows are hidden units: bias per (nt, quad, r)
    float4v b0v[4];
    float b1v[4], w2v[4];
#pragma unroll
    for (int nt = 0; nt < 4; nt++) {
#pragma unroll
        for (int r = 0; r < 4; r++)
            b0v[nt][r] = B0[nt * 16 + quad * 4 + r];
        b1v[nt] = B1[nt * 16 + n16];
        w2v[nt] = W2[nt * 16 + n16];
    }

    const float Ex = efield[b * 2 + 0];
    const float Ey = efield[b * 2 + 1];
    const float enorm = sqrtf(Ex * Ex + Ey * Ey);
    const float* meanws = (const float*)(ws + WS_MEAN);

    // zero the K-pad halves 16..31 once (never rewritten)
    *(int4*)(rows + lane * FSTRIDE + 16) = make_int4(0, 0, 0, 0);
    *(int4*)(rows + lane * FSTRIDE + 24) = make_int4(0, 0, 0, 0);

    float energy = 0.f;
#pragma unroll 1
    for (int t = 0; t < 4; ++t) {
        // ---- build feature row (14 live halves of K=32) ----
        float f0, f1, f2, f3;
        uint64_t ohi, ohj;
        if (!is_atom) {
            const int tile = bx + t * PAIR_BLOCKS;
            const int p = tile * 128 + tid;
            float Df = (float)(2047 * 2047 - 8 * p);
            int i = (int)((2047.0f - sqrtf(Df)) * 0.5f);
            i = i < 0 ? 0 : (i > 1022 ? 1022 : i);
            while (i * (2047 - i) / 2 > p) --i;
            while ((i + 1) * (2046 - i) / 2 <= p) ++i;
            const int j = p - i * (2047 - i) / 2 + i + 1;
            const float2* pos = (const float2*)positions + b * NA;
            float2 pi = pos[i], pj = pos[j];
            f0 = pi.x - pj.x; f1 = pi.y - pj.y;           // mean cancels
            f2 = sqrtf(f0 * f0 + f1 * f1);
            float inv = __builtin_amdgcn_rcpf(fmaxf(f2, 1e-12f));
            f3 = (Ex * f0 + Ey * f1) * inv;
            ohi = 0x3C00ull << (species[b * NA + i] * 16);
            ohj = 0x3C00ull << (species[b * NA + j] * 16);
        } else {
            const int n = ((bx - PAIR_BLOCKS) * 4 + t) * 128 + tid;
            float2 pn = ((const float2*)positions)[b * NA + n];
            f0 = pn.x - meanws[b * 2 + 0];
            f1 = pn.y - meanws[b * 2 + 1];
            f2 = Ex; f3 = Ey;
            ohi = 0x3C00ull << (species[b * NA + n] * 16);
            ohj = 0;
        }
        int4 lo, hi;
        lo.x = (int)pkf16(f0, f1);
        lo.y = (int)pkf16(f2, f3);
        lo.z = (int)pkf16(enorm, 0.f);
        lo.w = (int)(uint32_t)ohi;
        hi.x = (int)(uint32_t)(ohi >> 32);
        hi.y = (int)(uint32_t)ohj;
        hi.z = (int)(uint32_t)(ohj >> 32);
        hi.w = 0;
        *(int4*)(rows + lane * FSTRIDE) = lo;
        *(int4*)(rows + lane * FSTRIDE + 8) = hi;

        // ---- 4 row-groups, unrolled, B-frag prefetched one group ahead ----
        half8 bfc = *(const half8*)(rows + (0 * 16 + n16) * FSTRIDE + quad * 8);
#pragma unroll
        for (int g = 0; g < 4; ++g) {
            // L0 swapped: lane holds, for tile nt, h[row n16][nt*16+quad*4+r]
            float4v a1[4];
#pragma unroll
            for (int nt = 0; nt < 4; nt++)
                a1[nt] = __builtin_amdgcn_mfma_f32_16x16x32_f16(w0f[nt], bfc, b0v[nt], 0, 0, 0);

            half8 bfn;
            if (g < 3)
                bfn = *(const half8*)(rows + ((g + 1) * 16 + n16) * FSTRIDE + quad * 8);

            // ---- staged silu (16-wide): all exps, then all rcps ----
            float ex[16];
#pragma unroll
            for (int nt = 0; nt < 4; nt++)
#pragma unroll
                for (int r = 0; r < 4; r++)
                    ex[nt * 4 + r] = __expf(-a1[nt][r]);
#pragma unroll
            for (int i = 0; i < 16; i++)
                ex[i] = __builtin_amdgcn_rcpf(1.0f + ex[i]);

            // pack silu values into L1 A-frags via pkrtz (bit-cast via union)
            union { half8 v; fp16x2 p[4]; } H0, H1;
#pragma unroll
            for (int q = 0; q < 2; q++) {          // q=0 -> nt 0/1, q=1 -> nt 2/3
                const int e0 = q ? 2 : 0, e1 = q ? 3 : 1;
                H0.p[2 * q + 0] = __builtin_amdgcn_cvt_pkrtz(
                    a1[e0][0] * ex[e0 * 4 + 0], a1[e0][1] * ex[e0 * 4 + 1]);
                H0.p[2 * q + 1] = __builtin_amdgcn_cvt_pkrtz(
                    a1[e0][2] * ex[e0 * 4 + 2], a1[e0][3] * ex[e0 * 4 + 3]);
                H1.p[2 * q + 0] = __builtin_amdgcn_cvt_pkrtz(
                    a1[e1][0] * ex[e1 * 4 + 0], a1[e1][1] * ex[e1 * 4 + 1]);
                H1.p[2 * q + 1] = __builtin_amdgcn_cvt_pkrtz(
                    a1[e1][2] * ex[e1 * 4 + 2], a1[e1][3] * ex[e1 * 4 + 3]);
            }

            // L1 standard: A = h-frags, B = permuted W1
            float4v a2[4];
#pragma unroll
            for (int nt = 0; nt < 4; nt++) {
                float4v c = {b1v[nt], b1v[nt], b1v[nt], b1v[nt]};
                c = __builtin_amdgcn_mfma_f32_16x16x32_f16(H0.v, w1f[nt][0], c, 0, 0, 0);
                c = __builtin_amdgcn_mfma_f32_16x16x32_f16(H1.v, w1f[nt][1], c, 0, 0, 0);
                a2[nt] = c;
            }

            // ---- staged silu + W2 dot ----
            float ex2[16];
#pragma unroll
            for (int nt = 0; nt < 4; nt++)
#pragma unroll
                for (int r = 0; r < 4; r++)
                    ex2[nt * 4 + r] = __expf(-a2[nt][r]);
#pragma unroll
            for (int i = 0; i < 16; i++)
                ex2[i] = __builtin_amdgcn_rcpf(1.0f + ex2[i]);
#pragma unroll
            for (int nt = 0; nt < 4; nt++)
#pragma unroll
                for (int r = 0; r < 4; r++)
                    energy = fmaf(a2[nt][r] * ex2[nt * 4 + r], w2v[nt], energy);

            if (g < 3) bfc = bfn;
        }
    }

    // ---- wave reduction -> one atomicAdd per wave ----
#pragma unroll
    for (int off = 32; off > 0; off >>= 1)
        energy += __shfl_down(energy, off);
    if (lane == 0)
        atomicAdd(&out[b], energy);
}

// ---------------------------------------------------------------------------
extern "C" void kernel_launch(void* const* d_in, const int* in_sizes, int n_in,
                              void* d_out, int out_size, void* d_ws, size_t ws_size,
                              hipStream_t stream) {
    const float* positions = (const float*)d_in[0];
    const int*   species   = (const int*)  d_in[1];
    const float* efield    = (const float*)d_in[2];
    const float* embed     = (const float*)d_in[3];
    const float* aW0 = (const float*)d_in[4];
    const float* ab0 = (const float*)d_in[5];
    const float* aW1 = (const float*)d_in[6];
    const float* ab1 = (const float*)d_in[7];
    const float* aW2 = (const float*)d_in[8];
    const float* ab2 = (const float*)d_in[9];
    const float* pW0 = (const float*)d_in[10];
    const float* pb0 = (const float*)d_in[11];
    const float* pW1 = (const float*)d_in[12];
    const float* pb1 = (const float*)d_in[13];
    const float* pW2 = (const float*)d_in[14];
    const float* pb2 = (const float*)d_in[15];
    float* outp = (float*)d_out;
    char*  ws   = (char*)d_ws;

    prep_kernel<<<dim3(28), dim3(256), 0, stream>>>(
        positions, embed, aW0, aW1, ab2, pW0, pW1, pb2, ws, outp);
    mlp_kernel<<<dim3(GRID_X, NBATCH), dim3(128), 0, stream>>>(
        positions, species, efield,
        ab0, ab1, aW2, pb0, pb1, pW2,
        ws, outp);
}